// Round 9
// baseline (1374.411 us; speedup 1.0000x reference)
//
#include <hip/hip_runtime.h>
#include <hip/hip_bf16.h>

// ---------------------------------------------------------------------------
// StationFlowGCN: 5x GCNConv (+ReLU) -> node MLP head + edge MLP head.
// Strategy: CSR-by-dst built on device each launch (counting sort, no float
// atomics in aggregation), fp32 tiled GEMMs for node transforms, fully fused
// per-edge MLP for the edge head (weights via wave-uniform scalar loads).
// ---------------------------------------------------------------------------

__global__ __launch_bounds__(256) void init_kernel(float* deg, int* cnt, int N) {
  int i = blockIdx.x * 256 + threadIdx.x;
  if (i < N) { deg[i] = 1.0f; cnt[i] = 0; }  // self-loop weight 1.0 pre-added
}

__global__ __launch_bounds__(256) void edge_count_kernel(
    const int* __restrict__ dst, const float* __restrict__ ew,
    float* deg, int* cnt, int E) {
  int e = blockIdx.x * 256 + threadIdx.x;
  if (e < E) {
    int d = dst[e];
    atomicAdd(&deg[d], ew[e]);
    atomicAdd(&cnt[d], 1);
  }
}

__global__ __launch_bounds__(256) void dinv_kernel(float* deg, int N) {
  int i = blockIdx.x * 256 + threadIdx.x;
  if (i < N) {
    float d = deg[i];
    deg[i] = (d > 0.f) ? rsqrtf(d) : 0.f;  // in-place: deg -> dinv
  }
}

// One-block exclusive scan of cnt[N] -> rp[N+1]; also zeroes cnt for reuse as
// the fill cursor in csr_fill.
__global__ __launch_bounds__(1024) void scan_kernel(int* cnt, int* rp, int N) {
  __shared__ int part[1024];
  int t = threadIdx.x;
  int CH = (N + 1023) >> 10;
  int lo = t * CH;
  int hi = lo + CH; if (hi > N) hi = N;
  if (lo > N) lo = N;
  int s = 0;
  for (int i = lo; i < hi; ++i) s += cnt[i];
  part[t] = s;
  __syncthreads();
  for (int off = 1; off < 1024; off <<= 1) {
    int v = (t >= off) ? part[t - off] : 0;
    __syncthreads();
    part[t] += v;
    __syncthreads();
  }
  int run = part[t] - s;  // exclusive prefix of this chunk
  for (int i = lo; i < hi; ++i) {
    int c = cnt[i];
    rp[i] = run;
    run += c;
    cnt[i] = 0;
  }
  if (hi == N) rp[N] = run;  // all such threads write the same total
}

__global__ __launch_bounds__(256) void csr_fill_kernel(
    const int* __restrict__ src, const int* __restrict__ dst,
    const float* __restrict__ ew, const float* __restrict__ dinv,
    const int* __restrict__ rp, int* fill, int* col, float* val, int E) {
  int e = blockIdx.x * 256 + threadIdx.x;
  if (e < E) {
    int s = src[e], d = dst[e];
    int pos = rp[d] + atomicAdd(&fill[d], 1);
    col[pos] = s;
    val[pos] = dinv[s] * ew[e] * dinv[d];
  }
}

// Y[M,DOUT] = A[M,DIN] @ W[DIN,DOUT], fp32, LDS-tiled. BM=64, BK=32.
template <int DIN, int DOUT>
__global__ __launch_bounds__(256) void gemm_kernel(
    const float* __restrict__ A, const float* __restrict__ W,
    float* __restrict__ Y, int M) {
  constexpr int BM = 64, BK = 32;
  constexpr int TN = 4;
  constexpr int THREADS_N = DOUT / TN;       // 32 / 16 / 8
  constexpr int THREADS_M = 256 / THREADS_N; // 8 / 16 / 32
  constexpr int TM = BM / THREADS_M;         // 8 / 4 / 2
  __shared__ float As[BK][BM + 4];           // [k][m], padded
  __shared__ float4 Ws[BK][DOUT / 4];

  const int tid = threadIdx.x;
  const int m_base = blockIdx.x * BM;
  const int tn = tid % THREADS_N;
  const int tmi = tid / THREADS_N;
  const int m0 = tmi * TM;
  const int n0 = tn * TN;

  float acc[TM][TN];
#pragma unroll
  for (int a = 0; a < TM; ++a)
#pragma unroll
    for (int b = 0; b < TN; ++b) acc[a][b] = 0.f;

  for (int k0 = 0; k0 < DIN; k0 += BK) {
    // stage A tile: 64 rows x 32 k = 512 float4, 2 per thread
#pragma unroll
    for (int l = 0; l < 2; ++l) {
      int f = tid * 2 + l;
      int row = f >> 3;
      int kk = (f & 7) * 4;
      float4 v = make_float4(0.f, 0.f, 0.f, 0.f);
      int gr = m_base + row;
      if (gr < M) v = *(const float4*)&A[(size_t)gr * DIN + k0 + kk];
      As[kk + 0][row] = v.x;
      As[kk + 1][row] = v.y;
      As[kk + 2][row] = v.z;
      As[kk + 3][row] = v.w;
    }
    // stage W tile: 32 x DOUT
    constexpr int WF = BK * DOUT / 4;
    constexpr int WPT = WF / 256;  // 4 / 2 / 1
#pragma unroll
    for (int l = 0; l < WPT; ++l) {
      int f = tid + l * 256;
      int kk = f / (DOUT / 4);
      int n4 = f % (DOUT / 4);
      Ws[kk][n4] = *(const float4*)&W[(size_t)(k0 + kk) * DOUT + n4 * 4];
    }
    __syncthreads();
#pragma unroll
    for (int kk = 0; kk < BK; ++kk) {
      float4 wv = Ws[kk][tn];
      float af[TM];
#pragma unroll
      for (int a = 0; a < TM; ++a) af[a] = As[kk][m0 + a];
#pragma unroll
      for (int a = 0; a < TM; ++a) {
        acc[a][0] += af[a] * wv.x;
        acc[a][1] += af[a] * wv.y;
        acc[a][2] += af[a] * wv.z;
        acc[a][3] += af[a] * wv.w;
      }
    }
    __syncthreads();
  }
#pragma unroll
  for (int a = 0; a < TM; ++a) {
    int gr = m_base + m0 + a;
    if (gr < M) {
      float4 o = make_float4(acc[a][0], acc[a][1], acc[a][2], acc[a][3]);
      *(float4*)&Y[(size_t)gr * DOUT + n0] = o;
    }
  }
}

// H[i,:] = relu( b + dinv[i]^2 * Y[i,:] + sum_e val[e] * Y[col[e],:] )
template <int DOUT>
__global__ __launch_bounds__(256) void agg_kernel(
    const float* __restrict__ Y, const int* __restrict__ rp,
    const int* __restrict__ col, const float* __restrict__ val,
    const float* __restrict__ dinv, const float* __restrict__ bias,
    float* __restrict__ H, int N) {
  constexpr int TPN = DOUT / 4;   // threads per node
  constexpr int NPB = 256 / TPN;  // nodes per block
  int j = threadIdx.x / TPN;
  int c4 = (threadIdx.x % TPN) * 4;
  int i = blockIdx.x * NPB + j;
  if (i >= N) return;
  float di = dinv[i];
  float sn = di * di;
  float4 yv = *(const float4*)&Y[(size_t)i * DOUT + c4];
  float4 bv = *(const float4*)&bias[c4];
  float ax = bv.x + sn * yv.x;
  float ay = bv.y + sn * yv.y;
  float az = bv.z + sn * yv.z;
  float aw = bv.w + sn * yv.w;
  int e1 = rp[i + 1];
  for (int e = rp[i]; e < e1; ++e) {
    int s = col[e];
    float v = val[e];
    float4 q = *(const float4*)&Y[(size_t)s * DOUT + c4];
    ax += v * q.x;
    ay += v * q.y;
    az += v * q.z;
    aw += v * q.w;
  }
  float4 o = make_float4(fmaxf(ax, 0.f), fmaxf(ay, 0.f), fmaxf(az, 0.f),
                         fmaxf(aw, 0.f));
  *(float4*)&H[(size_t)i * DOUT + c4] = o;
}

__global__ __launch_bounds__(256) void node_head_kernel(
    const float* __restrict__ H, const float* __restrict__ W1,
    const float* __restrict__ b1, const float* __restrict__ W2,
    const float* __restrict__ b2, float* __restrict__ out, int N) {
  int i = blockIdx.x * 256 + threadIdx.x;
  if (i >= N) return;
  float h[32];
#pragma unroll
  for (int k = 0; k < 8; ++k) {
    float4 v = *(const float4*)&H[(size_t)i * 32 + k * 4];
    h[k * 4 + 0] = v.x; h[k * 4 + 1] = v.y; h[k * 4 + 2] = v.z; h[k * 4 + 3] = v.w;
  }
  float t[32];
#pragma unroll
  for (int o = 0; o < 32; ++o) t[o] = b1[o];
#pragma unroll
  for (int k = 0; k < 32; ++k) {
    float hk = h[k];
#pragma unroll
    for (int o = 0; o < 32; ++o) t[o] += hk * W1[k * 32 + o];
  }
#pragma unroll
  for (int o = 0; o < 32; ++o) t[o] = fmaxf(t[o], 0.f);
  float u[12];
#pragma unroll
  for (int o = 0; o < 12; ++o) u[o] = b2[o];
#pragma unroll
  for (int k = 0; k < 32; ++k) {
    float tk = t[k];
#pragma unroll
    for (int o = 0; o < 12; ++o) u[o] += tk * W2[k * 12 + o];
  }
#pragma unroll
  for (int o = 0; o < 12; ++o) u[o] = fmaxf(u[o], 0.f);
  float* op = out + (size_t)i * 12;
  *(float4*)&op[0] = make_float4(u[0], u[1], u[2], u[3]);
  *(float4*)&op[4] = make_float4(u[4], u[5], u[6], u[7]);
  *(float4*)&op[8] = make_float4(u[8], u[9], u[10], u[11]);
}

__global__ __launch_bounds__(256) void edge_head_kernel(
    const float* __restrict__ H, const int* __restrict__ src,
    const int* __restrict__ dst,
    const float* __restrict__ W1, const float* __restrict__ b1,
    const float* __restrict__ W2, const float* __restrict__ b2,
    const float* __restrict__ W3, const float* __restrict__ b3,
    const float* __restrict__ W4, const float* __restrict__ b4,
    float* __restrict__ out, int E) {
  int e = blockIdx.x * 256 + threadIdx.x;
  if (e >= E) return;
  int s = src[e], d = dst[e];
  float in[64];
#pragma unroll
  for (int k = 0; k < 8; ++k) {
    float4 v = *(const float4*)&H[(size_t)s * 32 + k * 4];
    in[k * 4 + 0] = v.x; in[k * 4 + 1] = v.y; in[k * 4 + 2] = v.z; in[k * 4 + 3] = v.w;
  }
#pragma unroll
  for (int k = 0; k < 8; ++k) {
    float4 v = *(const float4*)&H[(size_t)d * 32 + k * 4];
    in[32 + k * 4 + 0] = v.x; in[32 + k * 4 + 1] = v.y;
    in[32 + k * 4 + 2] = v.z; in[32 + k * 4 + 3] = v.w;
  }
  // layer 1: 64 -> 64
  float t1[64];
#pragma unroll
  for (int o = 0; o < 64; ++o) t1[o] = b1[o];
#pragma unroll
  for (int k = 0; k < 64; ++k) {
    float a = in[k];
#pragma unroll
    for (int o = 0; o < 64; ++o) t1[o] += a * W1[k * 64 + o];
  }
#pragma unroll
  for (int o = 0; o < 64; ++o) t1[o] = fmaxf(t1[o], 0.f);
  // layer 2: 64 -> 32
  float t2[32];
#pragma unroll
  for (int o = 0; o < 32; ++o) t2[o] = b2[o];
#pragma unroll
  for (int k = 0; k < 64; ++k) {
    float a = t1[k];
#pragma unroll
    for (int o = 0; o < 32; ++o) t2[o] += a * W2[k * 32 + o];
  }
#pragma unroll
  for (int o = 0; o < 32; ++o) t2[o] = fmaxf(t2[o], 0.f);
  // layer 3: 32 -> 32
  float t3[32];
#pragma unroll
  for (int o = 0; o < 32; ++o) t3[o] = b3[o];
#pragma unroll
  for (int k = 0; k < 32; ++k) {
    float a = t2[k];
#pragma unroll
    for (int o = 0; o < 32; ++o) t3[o] += a * W3[k * 32 + o];
  }
#pragma unroll
  for (int o = 0; o < 32; ++o) t3[o] = fmaxf(t3[o], 0.f);
  // layer 4: 32 -> 12
  float u[12];
#pragma unroll
  for (int o = 0; o < 12; ++o) u[o] = b4[o];
#pragma unroll
  for (int k = 0; k < 32; ++k) {
    float a = t3[k];
#pragma unroll
    for (int o = 0; o < 12; ++o) u[o] += a * W4[k * 12 + o];
  }
#pragma unroll
  for (int o = 0; o < 12; ++o) u[o] = fmaxf(u[o], 0.f);
  float* op = out + (size_t)e * 12;
  *(float4*)&op[0] = make_float4(u[0], u[1], u[2], u[3]);
  *(float4*)&op[4] = make_float4(u[4], u[5], u[6], u[7]);
  *(float4*)&op[8] = make_float4(u[8], u[9], u[10], u[11]);
}

extern "C" void kernel_launch(void* const* d_in, const int* in_sizes, int n_in,
                              void* d_out, int out_size, void* d_ws,
                              size_t ws_size, hipStream_t stream) {
  const float* x  = (const float*)d_in[0];
  const int* ei   = (const int*)d_in[1];
  const float* ew = (const float*)d_in[2];
  const float* W1 = (const float*)d_in[3];
  const float* b1 = (const float*)d_in[4];
  const float* W2 = (const float*)d_in[5];
  const float* b2 = (const float*)d_in[6];
  const float* W3 = (const float*)d_in[7];
  const float* b3 = (const float*)d_in[8];
  const float* W4 = (const float*)d_in[9];
  const float* b4 = (const float*)d_in[10];
  const float* W5 = (const float*)d_in[11];
  const float* b5 = (const float*)d_in[12];
  const float* nhW1 = (const float*)d_in[13];
  const float* nhb1 = (const float*)d_in[14];
  const float* nhW2 = (const float*)d_in[15];
  const float* nhb2 = (const float*)d_in[16];
  const float* eW1 = (const float*)d_in[17];
  const float* eb1 = (const float*)d_in[18];
  const float* eW2 = (const float*)d_in[19];
  const float* eb2 = (const float*)d_in[20];
  const float* eW3 = (const float*)d_in[21];
  const float* eb3 = (const float*)d_in[22];
  const float* eW4 = (const float*)d_in[23];
  const float* eb4 = (const float*)d_in[24];

  const int N = in_sizes[0] / 128;
  const int E = in_sizes[2];
  const int* srcp = ei;
  const int* dstp = ei + E;

  char* ws = (char*)d_ws;
  size_t off = 0;
  auto alloc = [&](size_t bytes) {
    char* p = ws + off;
    off = (off + bytes + 255) & ~(size_t)255;
    return p;
  };
  float* deg = (float*)alloc((size_t)N * 4);   // becomes dinv in-place
  int* cnt   = (int*)alloc((size_t)N * 4);     // histogram, then fill cursor
  int* rp    = (int*)alloc((size_t)(N + 1) * 4);
  int* col   = (int*)alloc((size_t)E * 4);
  float* val = (float*)alloc((size_t)E * 4);
  float* ybuf = (float*)alloc((size_t)N * 128 * 4);
  float* hA   = (float*)alloc((size_t)N * 128 * 4);
  float* hB   = (float*)alloc((size_t)N * 64 * 4);

  const int gN = (N + 255) / 256;
  const int gE = (E + 255) / 256;
  const int gM = (N + 63) / 64;

  init_kernel<<<gN, 256, 0, stream>>>(deg, cnt, N);
  edge_count_kernel<<<gE, 256, 0, stream>>>(dstp, ew, deg, cnt, E);
  dinv_kernel<<<gN, 256, 0, stream>>>(deg, N);
  scan_kernel<<<1, 1024, 0, stream>>>(cnt, rp, N);
  csr_fill_kernel<<<gE, 256, 0, stream>>>(srcp, dstp, ew, deg, rp, cnt, col, val, E);

  // layer 1: 128 -> 128
  gemm_kernel<128, 128><<<gM, 256, 0, stream>>>(x, W1, ybuf, N);
  agg_kernel<128><<<(N + 7) / 8, 256, 0, stream>>>(ybuf, rp, col, val, deg, b1, hA, N);
  // layer 2: 128 -> 64
  gemm_kernel<128, 64><<<gM, 256, 0, stream>>>(hA, W2, ybuf, N);
  agg_kernel<64><<<(N + 15) / 16, 256, 0, stream>>>(ybuf, rp, col, val, deg, b2, hB, N);
  // layer 3: 64 -> 64
  gemm_kernel<64, 64><<<gM, 256, 0, stream>>>(hB, W3, ybuf, N);
  agg_kernel<64><<<(N + 15) / 16, 256, 0, stream>>>(ybuf, rp, col, val, deg, b3, hA, N);
  // layer 4: 64 -> 32
  gemm_kernel<64, 32><<<gM, 256, 0, stream>>>(hA, W4, ybuf, N);
  agg_kernel<32><<<(N + 31) / 32, 256, 0, stream>>>(ybuf, rp, col, val, deg, b4, hB, N);
  // layer 5: 32 -> 32
  gemm_kernel<32, 32><<<gM, 256, 0, stream>>>(hB, W5, ybuf, N);
  agg_kernel<32><<<(N + 31) / 32, 256, 0, stream>>>(ybuf, rp, col, val, deg, b5, hA, N);

  float* node_out = (float*)d_out;
  float* edge_out = (float*)d_out + (size_t)N * 12;
  node_head_kernel<<<gN, 256, 0, stream>>>(hA, nhW1, nhb1, nhW2, nhb2, node_out, N);
  edge_head_kernel<<<gE, 256, 0, stream>>>(hA, srcp, dstp, eW1, eb1, eW2, eb2,
                                           eW3, eb3, eW4, eb4, edge_out, E);
}

// Round 11
// 1366.645 us; speedup vs baseline: 1.0057x; 1.0057x over previous
//
#include <hip/hip_runtime.h>
#include <hip/hip_bf16.h>

// ---------------------------------------------------------------------------
// StationFlowGCN: 5x GCNConv (+ReLU) -> node MLP head + edge MLP head.
// CSR-by-dst built on device (counting sort, no float atomics), fp32 tiled
// GEMMs, fused per-edge MLP. R9: edge_head rewritten with float2
// (ext_vector_type) math so the backend can emit v_pk_fma_f32 (packed 2xfp32
// FMA, bit-identical numerics) -- halves the VALU issue floor that rocprof
// showed we are bound by (484us @ VALUBusy 50%, HBM 5%).
// ---------------------------------------------------------------------------

typedef float f32x2 __attribute__((ext_vector_type(2)));

__global__ __launch_bounds__(256) void init_kernel(float* deg, int* cnt, int N) {
  int i = blockIdx.x * 256 + threadIdx.x;
  if (i < N) { deg[i] = 1.0f; cnt[i] = 0; }  // self-loop weight 1.0 pre-added
}

__global__ __launch_bounds__(256) void edge_count_kernel(
    const int* __restrict__ dst, const float* __restrict__ ew,
    float* deg, int* cnt, int E) {
  int e = blockIdx.x * 256 + threadIdx.x;
  if (e < E) {
    int d = dst[e];
    atomicAdd(&deg[d], ew[e]);
    atomicAdd(&cnt[d], 1);
  }
}

__global__ __launch_bounds__(256) void dinv_kernel(float* deg, int N) {
  int i = blockIdx.x * 256 + threadIdx.x;
  if (i < N) {
    float d = deg[i];
    deg[i] = (d > 0.f) ? rsqrtf(d) : 0.f;  // in-place: deg -> dinv
  }
}

// One-block exclusive scan of cnt[N] -> rp[N+1]; also zeroes cnt for reuse as
// the fill cursor in csr_fill.
__global__ __launch_bounds__(1024) void scan_kernel(int* cnt, int* rp, int N) {
  __shared__ int part[1024];
  int t = threadIdx.x;
  int CH = (N + 1023) >> 10;
  int lo = t * CH;
  int hi = lo + CH; if (hi > N) hi = N;
  if (lo > N) lo = N;
  int s = 0;
  for (int i = lo; i < hi; ++i) s += cnt[i];
  part[t] = s;
  __syncthreads();
  for (int off = 1; off < 1024; off <<= 1) {
    int v = (t >= off) ? part[t - off] : 0;
    __syncthreads();
    part[t] += v;
    __syncthreads();
  }
  int run = part[t] - s;  // exclusive prefix of this chunk
  for (int i = lo; i < hi; ++i) {
    int c = cnt[i];
    rp[i] = run;
    run += c;
    cnt[i] = 0;
  }
  if (hi == N) rp[N] = run;  // all such threads write the same total
}

__global__ __launch_bounds__(256) void csr_fill_kernel(
    const int* __restrict__ src, const int* __restrict__ dst,
    const float* __restrict__ ew, const float* __restrict__ dinv,
    const int* __restrict__ rp, int* fill, int* col, float* val, int E) {
  int e = blockIdx.x * 256 + threadIdx.x;
  if (e < E) {
    int s = src[e], d = dst[e];
    int pos = rp[d] + atomicAdd(&fill[d], 1);
    col[pos] = s;
    val[pos] = dinv[s] * ew[e] * dinv[d];
  }
}

// Y[M,DOUT] = A[M,DIN] @ W[DIN,DOUT], fp32, LDS-tiled. BM=64, BK=32.
template <int DIN, int DOUT>
__global__ __launch_bounds__(256) void gemm_kernel(
    const float* __restrict__ A, const float* __restrict__ W,
    float* __restrict__ Y, int M) {
  constexpr int BM = 64, BK = 32;
  constexpr int TN = 4;
  constexpr int THREADS_N = DOUT / TN;       // 32 / 16 / 8
  constexpr int THREADS_M = 256 / THREADS_N; // 8 / 16 / 32
  constexpr int TM = BM / THREADS_M;         // 8 / 4 / 2
  __shared__ float As[BK][BM + 4];           // [k][m], padded
  __shared__ float4 Ws[BK][DOUT / 4];

  const int tid = threadIdx.x;
  const int m_base = blockIdx.x * BM;
  const int tn = tid % THREADS_N;
  const int tmi = tid / THREADS_N;
  const int m0 = tmi * TM;
  const int n0 = tn * TN;

  float acc[TM][TN];
#pragma unroll
  for (int a = 0; a < TM; ++a)
#pragma unroll
    for (int b = 0; b < TN; ++b) acc[a][b] = 0.f;

  for (int k0 = 0; k0 < DIN; k0 += BK) {
    // stage A tile: 64 rows x 32 k = 512 float4, 2 per thread
#pragma unroll
    for (int l = 0; l < 2; ++l) {
      int f = tid * 2 + l;
      int row = f >> 3;
      int kk = (f & 7) * 4;
      float4 v = make_float4(0.f, 0.f, 0.f, 0.f);
      int gr = m_base + row;
      if (gr < M) v = *(const float4*)&A[(size_t)gr * DIN + k0 + kk];
      As[kk + 0][row] = v.x;
      As[kk + 1][row] = v.y;
      As[kk + 2][row] = v.z;
      As[kk + 3][row] = v.w;
    }
    // stage W tile: 32 x DOUT
    constexpr int WF = BK * DOUT / 4;
    constexpr int WPT = WF / 256;  // 4 / 2 / 1
#pragma unroll
    for (int l = 0; l < WPT; ++l) {
      int f = tid + l * 256;
      int kk = f / (DOUT / 4);
      int n4 = f % (DOUT / 4);
      Ws[kk][n4] = *(const float4*)&W[(size_t)(k0 + kk) * DOUT + n4 * 4];
    }
    __syncthreads();
#pragma unroll
    for (int kk = 0; kk < BK; ++kk) {
      float4 wv = Ws[kk][tn];
      float af[TM];
#pragma unroll
      for (int a = 0; a < TM; ++a) af[a] = As[kk][m0 + a];
#pragma unroll
      for (int a = 0; a < TM; ++a) {
        acc[a][0] += af[a] * wv.x;
        acc[a][1] += af[a] * wv.y;
        acc[a][2] += af[a] * wv.z;
        acc[a][3] += af[a] * wv.w;
      }
    }
    __syncthreads();
  }
#pragma unroll
  for (int a = 0; a < TM; ++a) {
    int gr = m_base + m0 + a;
    if (gr < M) {
      float4 o = make_float4(acc[a][0], acc[a][1], acc[a][2], acc[a][3]);
      *(float4*)&Y[(size_t)gr * DOUT + n0] = o;
    }
  }
}

// H[i,:] = relu( b + dinv[i]^2 * Y[i,:] + sum_e val[e] * Y[col[e],:] )
template <int DOUT>
__global__ __launch_bounds__(256) void agg_kernel(
    const float* __restrict__ Y, const int* __restrict__ rp,
    const int* __restrict__ col, const float* __restrict__ val,
    const float* __restrict__ dinv, const float* __restrict__ bias,
    float* __restrict__ H, int N) {
  constexpr int TPN = DOUT / 4;   // threads per node
  constexpr int NPB = 256 / TPN;  // nodes per block
  int j = threadIdx.x / TPN;
  int c4 = (threadIdx.x % TPN) * 4;
  int i = blockIdx.x * NPB + j;
  if (i >= N) return;
  float di = dinv[i];
  float sn = di * di;
  float4 yv = *(const float4*)&Y[(size_t)i * DOUT + c4];
  float4 bv = *(const float4*)&bias[c4];
  float ax = bv.x + sn * yv.x;
  float ay = bv.y + sn * yv.y;
  float az = bv.z + sn * yv.z;
  float aw = bv.w + sn * yv.w;
  int e1 = rp[i + 1];
  for (int e = rp[i]; e < e1; ++e) {
    int s = col[e];
    float v = val[e];
    float4 q = *(const float4*)&Y[(size_t)s * DOUT + c4];
    ax += v * q.x;
    ay += v * q.y;
    az += v * q.z;
    aw += v * q.w;
  }
  float4 o = make_float4(fmaxf(ax, 0.f), fmaxf(ay, 0.f), fmaxf(az, 0.f),
                         fmaxf(aw, 0.f));
  *(float4*)&H[(size_t)i * DOUT + c4] = o;
}

__global__ __launch_bounds__(256) void node_head_kernel(
    const float* __restrict__ H, const float* __restrict__ W1,
    const float* __restrict__ b1, const float* __restrict__ W2,
    const float* __restrict__ b2, float* __restrict__ out, int N) {
  int i = blockIdx.x * 256 + threadIdx.x;
  if (i >= N) return;
  float h[32];
#pragma unroll
  for (int k = 0; k < 8; ++k) {
    float4 v = *(const float4*)&H[(size_t)i * 32 + k * 4];
    h[k * 4 + 0] = v.x; h[k * 4 + 1] = v.y; h[k * 4 + 2] = v.z; h[k * 4 + 3] = v.w;
  }
  float t[32];
#pragma unroll
  for (int o = 0; o < 32; ++o) t[o] = b1[o];
#pragma unroll
  for (int k = 0; k < 32; ++k) {
    float hk = h[k];
#pragma unroll
    for (int o = 0; o < 32; ++o) t[o] += hk * W1[k * 32 + o];
  }
#pragma unroll
  for (int o = 0; o < 32; ++o) t[o] = fmaxf(t[o], 0.f);
  float u[12];
#pragma unroll
  for (int o = 0; o < 12; ++o) u[o] = b2[o];
#pragma unroll
  for (int k = 0; k < 32; ++k) {
    float tk = t[k];
#pragma unroll
    for (int o = 0; o < 12; ++o) u[o] += tk * W2[k * 12 + o];
  }
#pragma unroll
  for (int o = 0; o < 12; ++o) u[o] = fmaxf(u[o], 0.f);
  float* op = out + (size_t)i * 12;
  *(float4*)&op[0] = make_float4(u[0], u[1], u[2], u[3]);
  *(float4*)&op[4] = make_float4(u[4], u[5], u[6], u[7]);
  *(float4*)&op[8] = make_float4(u[8], u[9], u[10], u[11]);
}

// Edge head, packed-fp32 version. All accumulators / weights are f32x2 so the
// backend can select v_pk_fma_f32 (VOP3P): identical numerics to scalar FMA
// (same fused op, same per-output k-order), half the VALU issue slots.
__global__ __launch_bounds__(256) void edge_head_kernel(
    const float* __restrict__ H, const int* __restrict__ src,
    const int* __restrict__ dst,
    const float* __restrict__ W1, const float* __restrict__ b1,
    const float* __restrict__ W2, const float* __restrict__ b2,
    const float* __restrict__ W3, const float* __restrict__ b3,
    const float* __restrict__ W4, const float* __restrict__ b4,
    float* __restrict__ out, int E) {
  int e = blockIdx.x * 256 + threadIdx.x;
  if (e >= E) return;
  int s = src[e], d = dst[e];

  // Gather both H rows up front: 16 independent dwordx4 loads, one vmcnt batch.
  float4 in4[16];
#pragma unroll
  for (int k = 0; k < 8; ++k)
    in4[k] = *(const float4*)&H[(size_t)s * 32 + k * 4];
#pragma unroll
  for (int k = 0; k < 8; ++k)
    in4[8 + k] = *(const float4*)&H[(size_t)d * 32 + k * 4];
  const float* in = (const float*)in4;  // 64 activations

  const f32x2* W1v = (const f32x2*)W1;  // [k][32] pairs over o
  const f32x2* W2v = (const f32x2*)W2;  // [k][16]
  const f32x2* W3v = (const f32x2*)W3;  // [k][16]
  const f32x2* W4v = (const f32x2*)W4;  // [k][6]
  const f32x2* b1v = (const f32x2*)b1;
  const f32x2* b2v = (const f32x2*)b2;
  const f32x2* b3v = (const f32x2*)b3;
  const f32x2* b4v = (const f32x2*)b4;

  // layer 1: 64 -> 64 (32 pairs)
  f32x2 t1[32];
#pragma unroll
  for (int o = 0; o < 32; ++o) t1[o] = b1v[o];
#pragma unroll
  for (int k = 0; k < 64; ++k) {
    float a = in[k];
    f32x2 aa = {a, a};
#pragma unroll
    for (int o = 0; o < 32; ++o) t1[o] += aa * W1v[k * 32 + o];
  }
#pragma unroll
  for (int o = 0; o < 32; ++o) {
    t1[o].x = fmaxf(t1[o].x, 0.f);
    t1[o].y = fmaxf(t1[o].y, 0.f);
  }
  // layer 2: 64 -> 32 (16 pairs)
  f32x2 t2[16];
#pragma unroll
  for (int o = 0; o < 16; ++o) t2[o] = b2v[o];
#pragma unroll
  for (int k = 0; k < 64; ++k) {
    float a = t1[k >> 1][k & 1];
    f32x2 aa = {a, a};
#pragma unroll
    for (int o = 0; o < 16; ++o) t2[o] += aa * W2v[k * 16 + o];
  }
#pragma unroll
  for (int o = 0; o < 16; ++o) {
    t2[o].x = fmaxf(t2[o].x, 0.f);
    t2[o].y = fmaxf(t2[o].y, 0.f);
  }
  // layer 3: 32 -> 32 (16 pairs)
  f32x2 t3[16];
#pragma unroll
  for (int o = 0; o < 16; ++o) t3[o] = b3v[o];
#pragma unroll
  for (int k = 0; k < 32; ++k) {
    float a = t2[k >> 1][k & 1];
    f32x2 aa = {a, a};
#pragma unroll
    for (int o = 0; o < 16; ++o) t3[o] += aa * W3v[k * 16 + o];
  }
#pragma unroll
  for (int o = 0; o < 16; ++o) {
    t3[o].x = fmaxf(t3[o].x, 0.f);
    t3[o].y = fmaxf(t3[o].y, 0.f);
  }
  // layer 4: 32 -> 12 (6 pairs)
  f32x2 u[6];
#pragma unroll
  for (int o = 0; o < 6; ++o) u[o] = b4v[o];
#pragma unroll
  for (int k = 0; k < 32; ++k) {
    float a = t3[k >> 1][k & 1];
    f32x2 aa = {a, a};
#pragma unroll
    for (int o = 0; o < 6; ++o) u[o] += aa * W4v[k * 6 + o];
  }
  float uo[12];
#pragma unroll
  for (int o = 0; o < 6; ++o) {
    uo[2 * o + 0] = fmaxf(u[o].x, 0.f);
    uo[2 * o + 1] = fmaxf(u[o].y, 0.f);
  }
  float* op = out + (size_t)e * 12;
  *(float4*)&op[0] = make_float4(uo[0], uo[1], uo[2], uo[3]);
  *(float4*)&op[4] = make_float4(uo[4], uo[5], uo[6], uo[7]);
  *(float4*)&op[8] = make_float4(uo[8], uo[9], uo[10], uo[11]);
}

extern "C" void kernel_launch(void* const* d_in, const int* in_sizes, int n_in,
                              void* d_out, int out_size, void* d_ws,
                              size_t ws_size, hipStream_t stream) {
  const float* x  = (const float*)d_in[0];
  const int* ei   = (const int*)d_in[1];
  const float* ew = (const float*)d_in[2];
  const float* W1 = (const float*)d_in[3];
  const float* b1 = (const float*)d_in[4];
  const float* W2 = (const float*)d_in[5];
  const float* b2 = (const float*)d_in[6];
  const float* W3 = (const float*)d_in[7];
  const float* b3 = (const float*)d_in[8];
  const float* W4 = (const float*)d_in[9];
  const float* b4 = (const float*)d_in[10];
  const float* W5 = (const float*)d_in[11];
  const float* b5 = (const float*)d_in[12];
  const float* nhW1 = (const float*)d_in[13];
  const float* nhb1 = (const float*)d_in[14];
  const float* nhW2 = (const float*)d_in[15];
  const float* nhb2 = (const float*)d_in[16];
  const float* eW1 = (const float*)d_in[17];
  const float* eb1 = (const float*)d_in[18];
  const float* eW2 = (const float*)d_in[19];
  const float* eb2 = (const float*)d_in[20];
  const float* eW3 = (const float*)d_in[21];
  const float* eb3 = (const float*)d_in[22];
  const float* eW4 = (const float*)d_in[23];
  const float* eb4 = (const float*)d_in[24];

  const int N = in_sizes[0] / 128;
  const int E = in_sizes[2];
  const int* srcp = ei;
  const int* dstp = ei + E;

  char* ws = (char*)d_ws;
  size_t off = 0;
  auto alloc = [&](size_t bytes) {
    char* p = ws + off;
    off = (off + bytes + 255) & ~(size_t)255;
    return p;
  };
  float* deg = (float*)alloc((size_t)N * 4);   // becomes dinv in-place
  int* cnt   = (int*)alloc((size_t)N * 4);     // histogram, then fill cursor
  int* rp    = (int*)alloc((size_t)(N + 1) * 4);
  int* col   = (int*)alloc((size_t)E * 4);
  float* val = (float*)alloc((size_t)E * 4);
  float* ybuf = (float*)alloc((size_t)N * 128 * 4);
  float* hA   = (float*)alloc((size_t)N * 128 * 4);
  float* hB   = (float*)alloc((size_t)N * 64 * 4);

  const int gN = (N + 255) / 256;
  const int gE = (E + 255) / 256;
  const int gM = (N + 63) / 64;

  init_kernel<<<gN, 256, 0, stream>>>(deg, cnt, N);
  edge_count_kernel<<<gE, 256, 0, stream>>>(dstp, ew, deg, cnt, E);
  dinv_kernel<<<gN, 256, 0, stream>>>(deg, N);
  scan_kernel<<<1, 1024, 0, stream>>>(cnt, rp, N);
  csr_fill_kernel<<<gE, 256, 0, stream>>>(srcp, dstp, ew, deg, rp, cnt, col, val, E);

  // layer 1: 128 -> 128
  gemm_kernel<128, 128><<<gM, 256, 0, stream>>>(x, W1, ybuf, N);
  agg_kernel<128><<<(N + 7) / 8, 256, 0, stream>>>(ybuf, rp, col, val, deg, b1, hA, N);
  // layer 2: 128 -> 64
  gemm_kernel<128, 64><<<gM, 256, 0, stream>>>(hA, W2, ybuf, N);
  agg_kernel<64><<<(N + 15) / 16, 256, 0, stream>>>(ybuf, rp, col, val, deg, b2, hB, N);
  // layer 3: 64 -> 64
  gemm_kernel<64, 64><<<gM, 256, 0, stream>>>(hB, W3, ybuf, N);
  agg_kernel<64><<<(N + 15) / 16, 256, 0, stream>>>(ybuf, rp, col, val, deg, b3, hA, N);
  // layer 4: 64 -> 32
  gemm_kernel<64, 32><<<gM, 256, 0, stream>>>(hA, W4, ybuf, N);
  agg_kernel<32><<<(N + 31) / 32, 256, 0, stream>>>(ybuf, rp, col, val, deg, b4, hB, N);
  // layer 5: 32 -> 32
  gemm_kernel<32, 32><<<gM, 256, 0, stream>>>(hB, W5, ybuf, N);
  agg_kernel<32><<<(N + 31) / 32, 256, 0, stream>>>(ybuf, rp, col, val, deg, b5, hA, N);

  float* node_out = (float*)d_out;
  float* edge_out = (float*)d_out + (size_t)N * 12;
  node_head_kernel<<<gN, 256, 0, stream>>>(hA, nhW1, nhb1, nhW2, nhb2, node_out, N);
  edge_head_kernel<<<gE, 256, 0, stream>>>(hA, srcp, dstp, eW1, eb1, eW2, eb2,
                                           eW3, eb3, eW4, eb4, edge_out, E);
}